// Round 1
// 1460.551 us; speedup vs baseline: 3.0634x; 3.0634x over previous
//
#include <hip/hip_runtime.h>

#define EPS_F 0.001f

constexpr int Nn = 16;
constexpr int Cc = 64;
constexpr int Tt = 64;
constexpr int Vv = 384;
constexpr size_t TV = (size_t)Tt * Vv;      // 24576
constexpr size_t VW = (size_t)Vv * Vv;      // 147456
constexpr size_t OUT0 = (size_t)Nn * Cc * TV;   // 25165824 floats (out)
// An: Nn*Cc*VW = 150994944 floats, appended after out in d_out

// ---------------- Kernel 1: xc[n,o,t,v] = sum_c x[n,c,t,v]*cw[o,c] + cb[o] ----
__global__ __launch_bounds__(256) void k_conv(const float* __restrict__ x,
        const float* __restrict__ cw, const float* __restrict__ cb,
        float* __restrict__ xc) {
    __shared__ float wt[64 * 64];   // transposed: wt[c*64+o]
    const int tid = threadIdx.x;
    for (int i = tid; i < 4096; i += 256) {
        int o = i & 63, c = i >> 6;
        wt[c * 64 + o] = cw[o * 64 + c];
    }
    __syncthreads();
    const int b = blockIdx.x;            // 768 blocks, 48 per n
    const int n = b / 48;
    const int pos = (b % 48) * 512 + tid;   // this thread handles pos and pos+256
    const float* xin = x + (size_t)n * Cc * TV + pos;
    float acc0[64], acc1[64];
#pragma unroll
    for (int o = 0; o < 64; ++o) { acc0[o] = 0.f; acc1[o] = 0.f; }
    for (int c = 0; c < 64; ++c) {
        float x0 = xin[(size_t)c * TV];
        float x1 = xin[(size_t)c * TV + 256];
        const float4* wr = (const float4*)(wt + c * 64);
#pragma unroll
        for (int oq = 0; oq < 16; ++oq) {
            float4 w4 = wr[oq];
            acc0[oq*4+0] += x0 * w4.x; acc0[oq*4+1] += x0 * w4.y;
            acc0[oq*4+2] += x0 * w4.z; acc0[oq*4+3] += x0 * w4.w;
            acc1[oq*4+0] += x1 * w4.x; acc1[oq*4+1] += x1 * w4.y;
            acc1[oq*4+2] += x1 * w4.z; acc1[oq*4+3] += x1 * w4.w;
        }
    }
    float* xo = xc + (size_t)n * Cc * TV + pos;
#pragma unroll
    for (int o = 0; o < 64; ++o) {
        float bo = cb[o];
        xo[(size_t)o * TV]       = acc0[o] + bo;
        xo[(size_t)o * TV + 256] = acc1[o] + bo;
    }
}

// ---------------- MLP layers 1-2 (weights via uniform/scalar loads) ----------
__device__ __forceinline__ void mlp12(const float a[8],
        const float* __restrict__ w1, const float* __restrict__ b1,
        const float* __restrict__ w2, const float* __restrict__ b2,
        float h2[32]) {
    float h1[16];
#pragma unroll
    for (int o = 0; o < 16; ++o) {
        float t = b1[o];
#pragma unroll
        for (int k = 0; k < 7; ++k) t += w1[o * 7 + k] * a[k];
        h1[o] = fmaxf(t, 0.f);
    }
#pragma unroll
    for (int o = 0; o < 32; ++o) {
        float t = b2[o];
#pragma unroll
        for (int i = 0; i < 16; ++i) t += w2[o * 16 + i] * h1[i];
        h2[o] = fmaxf(t, 0.f);
    }
}

// ---------------- Kernel 2: Am[n,c,v,w] = relu(mlp(A))*mask  (UNscaled) ------
// One MLP evaluation per (n,v,w) — computed exactly ONCE for the whole op.
__global__ __launch_bounds__(384) void k_am(const float* __restrict__ A,
        const float* __restrict__ w1, const float* __restrict__ b1,
        const float* __restrict__ w2, const float* __restrict__ b2,
        const float* __restrict__ w3, const float* __restrict__ b3,
        float* __restrict__ Am) {
    const int tid = threadIdx.x;        // w
    const int b = blockIdx.x;           // n*384 + v
    const int n = b / 384;
    const int v = b % 384;
    const float* Ab = A + (size_t)n * 8 * VW + (size_t)v * Vv + tid;
    float a[8];
#pragma unroll
    for (int k = 0; k < 8; ++k) a[k] = Ab[(size_t)k * VW];
    float h2[32];
    mlp12(a, w1, b1, w2, b2, h2);
    const float mask = a[7];
    float* ap = Am + (size_t)n * 64 * VW + (size_t)v * Vv + tid;
#pragma unroll
    for (int o = 0; o < 64; ++o) {
        float t = b3[o];
#pragma unroll
        for (int i = 0; i < 32; ++i) t += w3[o * 32 + i] * h2[i];
        ap[(size_t)o * VW] = fmaxf(t, 0.f) * mask;
    }
}

// ---------------- Kernel 3: Dlr[n,c,w] = 1/(sum_v Am[n,c,v,w] + eps) ---------
// Pure streaming column-reduction over Am (604 MB read), fused reciprocal.
__global__ __launch_bounds__(384) void k_red(const float* __restrict__ Am,
        float* __restrict__ Dlr) {
    __shared__ float4 part[4][96];
    const int tid = threadIdx.x;
    const int wi = tid % 96;            // float4 column index (96*4 = 384 w)
    const int vq = tid / 96;            // v quarter: 0..3
    const int b = blockIdx.x;           // n*64 + c, 1024 blocks
    const float4* p = (const float4*)(Am + (size_t)b * VW) + wi;
    float4 s = make_float4(0.f, 0.f, 0.f, 0.f);
#pragma unroll 4
    for (int v = vq * 96; v < vq * 96 + 96; ++v) {
        float4 t = p[(size_t)v * 96];
        s.x += t.x; s.y += t.y; s.z += t.z; s.w += t.w;
    }
    part[vq][wi] = s;
    __syncthreads();
    if (vq == 0) {
        float4 s0 = part[0][wi], s1 = part[1][wi], s2 = part[2][wi], s3 = part[3][wi];
        float4 r;
        r.x = 1.f / ((s0.x + s1.x) + (s2.x + s3.x) + EPS_F);
        r.y = 1.f / ((s0.y + s1.y) + (s2.y + s3.y) + EPS_F);
        r.z = 1.f / ((s0.z + s1.z) + (s2.z + s3.z) + EPS_F);
        r.w = 1.f / ((s0.w + s1.w) + (s2.w + s3.w) + EPS_F);
        *((float4*)(Dlr + (size_t)b * Vv) + wi) = r;
    }
}

// ---------------- Kernel 4: out[b,t,w] = sum_v xc[b,t,v]*(Am*Dlr)[b,v,w] -----
// Each An element is read by exactly one block (disjoint batch/w-tile), so the
// Dlr scaling is applied on load and the scaled value written back in place.
__global__ __launch_bounds__(256) void k_gemm(const float* __restrict__ xc,
        float* __restrict__ An, const float* __restrict__ Dlr,
        float* __restrict__ out) {
    __shared__ float As[16 * 68];   // [k][t], padded
    __shared__ float Bs[16 * 68];   // [k][w], padded
    const int tid = threadIdx.x;
    const int b = blockIdx.x;
    const int batch = b / 6;            // n*64+c
    const int w0 = (b % 6) * 64;
    const float* Ap = xc + (size_t)batch * TV;        // 64 x 384
    float* Bp = An + (size_t)batch * VW + w0;         // 384 x 384 (+col offset)
    const int ty = tid / 16, tx = tid % 16;
    const int lr = tid / 4,  lq = tid % 4;   // A-tile loader: row, k-quad
    const int br = tid / 16, bc = tid % 16;  // B-tile loader: k-row, w-quad
    const float4 dl4 = *(const float4*)(Dlr + (size_t)batch * Vv + w0 + bc * 4);
    float acc[4][4];
#pragma unroll
    for (int i = 0; i < 4; ++i)
#pragma unroll
        for (int j = 0; j < 4; ++j) acc[i][j] = 0.f;
    for (int k0 = 0; k0 < 384; k0 += 16) {
        float4 a4 = *(const float4*)(Ap + (size_t)lr * 384 + k0 + lq * 4);
        float4 b4 = *(const float4*)(Bp + (size_t)(k0 + br) * 384 + bc * 4);
        b4.x *= dl4.x; b4.y *= dl4.y; b4.z *= dl4.z; b4.w *= dl4.w;
        // write the final (scaled) An value back — each element exactly once
        *(float4*)(Bp + (size_t)(k0 + br) * 384 + bc * 4) = b4;
        As[(lq*4+0)*68 + lr] = a4.x;
        As[(lq*4+1)*68 + lr] = a4.y;
        As[(lq*4+2)*68 + lr] = a4.z;
        As[(lq*4+3)*68 + lr] = a4.w;
        *(float4*)(Bs + br * 68 + bc * 4) = b4;
        __syncthreads();
#pragma unroll
        for (int kk = 0; kk < 16; ++kk) {
            float4 av = *(const float4*)(As + kk * 68 + ty * 4);
            float4 bv = *(const float4*)(Bs + kk * 68 + tx * 4);
            float aa[4] = {av.x, av.y, av.z, av.w};
            float bb[4] = {bv.x, bv.y, bv.z, bv.w};
#pragma unroll
            for (int i = 0; i < 4; ++i)
#pragma unroll
                for (int j = 0; j < 4; ++j) acc[i][j] += aa[i] * bb[j];
        }
        __syncthreads();
    }
    float* op = out + (size_t)batch * TV + w0 + tx * 4;
#pragma unroll
    for (int i = 0; i < 4; ++i) {
        float4 o4 = make_float4(acc[i][0], acc[i][1], acc[i][2], acc[i][3]);
        *(float4*)(op + (size_t)(ty * 4 + i) * 384) = o4;
    }
}

extern "C" void kernel_launch(void* const* d_in, const int* in_sizes, int n_in,
                              void* d_out, int out_size, void* d_ws, size_t ws_size,
                              hipStream_t stream) {
    const float* x  = (const float*)d_in[0];
    const float* A  = (const float*)d_in[1];
    const float* cw = (const float*)d_in[2];
    const float* cb = (const float*)d_in[3];
    const float* w1 = (const float*)d_in[4];
    const float* b1 = (const float*)d_in[5];
    const float* w2 = (const float*)d_in[6];
    const float* b2 = (const float*)d_in[7];
    const float* w3 = (const float*)d_in[8];
    const float* b3 = (const float*)d_in[9];

    float* out = (float*)d_out;
    float* An  = out + OUT0;                 // An output region (holds raw Am,
                                             // then scaled An after k_gemm)
    float* xc  = (float*)d_ws;               // 25165824 floats = 100.7 MB
    float* Dlr = xc + OUT0;                  // 393216 floats  = 1.5 MB

    k_conv<<<768, 256, 0, stream>>>(x, cw, cb, xc);
    k_am  <<<6144, 384, 0, stream>>>(A, w1, b1, w2, b2, w3, b3, An);
    k_red <<<1024, 384, 0, stream>>>(An, Dlr);
    k_gemm<<<6144, 256, 0, stream>>>(xc, An, Dlr, out);
}

// Round 2
// 1431.445 us; speedup vs baseline: 3.1256x; 1.0203x over previous
//
#include <hip/hip_runtime.h>

#define EPS_F 0.001f

constexpr int Nn = 16;
constexpr int Cc = 64;
constexpr int Tt = 64;
constexpr int Vv = 384;
constexpr size_t TV = (size_t)Tt * Vv;      // 24576
constexpr size_t VW = (size_t)Vv * Vv;      // 147456
constexpr size_t OUT0 = (size_t)Nn * Cc * TV;   // 25165824 floats (out)
// An: Nn*Cc*VW = 150994944 floats, appended after out in d_out

// ---------------- Kernel 1: xc[n,o,t,v] = sum_c x[n,c,t,v]*cw[o,c] + cb[o] ----
__global__ __launch_bounds__(256) void k_conv(const float* __restrict__ x,
        const float* __restrict__ cw, const float* __restrict__ cb,
        float* __restrict__ xc) {
    __shared__ float wt[64 * 64];   // transposed: wt[c*64+o]
    const int tid = threadIdx.x;
    for (int i = tid; i < 4096; i += 256) {
        int o = i & 63, c = i >> 6;
        wt[c * 64 + o] = cw[o * 64 + c];
    }
    __syncthreads();
    const int b = blockIdx.x;            // 768 blocks, 48 per n
    const int n = b / 48;
    const int pos = (b % 48) * 512 + tid;   // this thread handles pos and pos+256
    const float* xin = x + (size_t)n * Cc * TV + pos;
    float acc0[64], acc1[64];
#pragma unroll
    for (int o = 0; o < 64; ++o) { acc0[o] = 0.f; acc1[o] = 0.f; }
    for (int c = 0; c < 64; ++c) {
        float x0 = xin[(size_t)c * TV];
        float x1 = xin[(size_t)c * TV + 256];
        const float4* wr = (const float4*)(wt + c * 64);
#pragma unroll
        for (int oq = 0; oq < 16; ++oq) {
            float4 w4 = wr[oq];
            acc0[oq*4+0] += x0 * w4.x; acc0[oq*4+1] += x0 * w4.y;
            acc0[oq*4+2] += x0 * w4.z; acc0[oq*4+3] += x0 * w4.w;
            acc1[oq*4+0] += x1 * w4.x; acc1[oq*4+1] += x1 * w4.y;
            acc1[oq*4+2] += x1 * w4.z; acc1[oq*4+3] += x1 * w4.w;
        }
    }
    float* xo = xc + (size_t)n * Cc * TV + pos;
#pragma unroll
    for (int o = 0; o < 64; ++o) {
        float bo = cb[o];
        xo[(size_t)o * TV]       = acc0[o] + bo;
        xo[(size_t)o * TV + 256] = acc1[o] + bo;
    }
}

// ---------------- MLP layers 1-2 (weights via uniform/scalar loads) ----------
__device__ __forceinline__ void mlp12(const float a[8],
        const float* __restrict__ w1, const float* __restrict__ b1,
        const float* __restrict__ w2, const float* __restrict__ b2,
        float h2[32]) {
    float h1[16];
#pragma unroll
    for (int o = 0; o < 16; ++o) {
        float t = b1[o];
#pragma unroll
        for (int k = 0; k < 7; ++k) t += w1[o * 7 + k] * a[k];
        h1[o] = fmaxf(t, 0.f);
    }
#pragma unroll
    for (int o = 0; o < 32; ++o) {
        float t = b2[o];
#pragma unroll
        for (int i = 0; i < 16; ++i) t += w2[o * 16 + i] * h1[i];
        h2[o] = fmaxf(t, 0.f);
    }
}

// ---------------- Kernel 2: Am[n,c,v,w] = relu(mlp(A))*mask  (UNscaled) ------
// One MLP evaluation per (n,v,w) — computed exactly ONCE for the whole op.
__global__ __launch_bounds__(384) void k_am(const float* __restrict__ A,
        const float* __restrict__ w1, const float* __restrict__ b1,
        const float* __restrict__ w2, const float* __restrict__ b2,
        const float* __restrict__ w3, const float* __restrict__ b3,
        float* __restrict__ Am) {
    const int tid = threadIdx.x;        // w
    const int b = blockIdx.x;           // n*384 + v
    const int n = b / 384;
    const int v = b % 384;
    const float* Ab = A + (size_t)n * 8 * VW + (size_t)v * Vv + tid;
    float a[8];
#pragma unroll
    for (int k = 0; k < 8; ++k) a[k] = Ab[(size_t)k * VW];
    float h2[32];
    mlp12(a, w1, b1, w2, b2, h2);
    const float mask = a[7];
    float* ap = Am + (size_t)n * 64 * VW + (size_t)v * Vv + tid;
#pragma unroll
    for (int o = 0; o < 64; ++o) {
        float t = b3[o];
#pragma unroll
        for (int i = 0; i < 32; ++i) t += w3[o * 32 + i] * h2[i];
        ap[(size_t)o * VW] = fmaxf(t, 0.f) * mask;
    }
}

// ---------------- Kernel 3: GEMM + fused column-sum + in-place An scaling ----
// out[b,t,w] = Dlr[b,w] * sum_v xc[b,t,v]*Am[b,v,w];  An = Am * Dlr.
// Dlr depends only on (b,w), so it factors out of the GEMM. Each block streams
// its FULL 384x64 B-panel, so the column sums are accumulated as a by-product
// of the B-tile loads. Epilogue: Dlr from LDS reduce, scale acc -> out, then
// one sweep over the (L2-resident) B-panel scaling Am -> An in place.
__global__ __launch_bounds__(256) void k_gemm(const float* __restrict__ xc,
        float* __restrict__ An, float* __restrict__ out) {
    __shared__ float As[16 * 68];          // [k][t], padded
    __shared__ float Bs[16 * 68];          // [k][w], padded
    __shared__ float4 part[256];           // per-thread colsum partials
    __shared__ __align__(16) float dlr[64];
    const int tid = threadIdx.x;
    const int b = blockIdx.x;
    const int batch = b / 6;            // n*64+c
    const int w0 = (b % 6) * 64;
    const float* Ap = xc + (size_t)batch * TV;   // 64 x 384
    float* Bp = An + (size_t)batch * VW + w0;    // 384 x 384 (+col offset), raw Am
    const int ty = tid / 16, tx = tid % 16;
    const int lr = tid / 4,  lq = tid % 4;   // A-tile loader: row, k-quad
    const int br = tid / 16, bc = tid % 16;  // B-tile loader: k-row, w-quad
    float acc[4][4];
#pragma unroll
    for (int i = 0; i < 4; ++i)
#pragma unroll
        for (int j = 0; j < 4; ++j) acc[i][j] = 0.f;
    float4 cs = make_float4(0.f, 0.f, 0.f, 0.f);   // colsum partial (4 cols)
    for (int k0 = 0; k0 < 384; k0 += 16) {
        float4 a4 = *(const float4*)(Ap + (size_t)lr * 384 + k0 + lq * 4);
        float4 b4 = *(const float4*)(Bp + (size_t)(k0 + br) * 384 + bc * 4);
        cs.x += b4.x; cs.y += b4.y; cs.z += b4.z; cs.w += b4.w;
        As[(lq*4+0)*68 + lr] = a4.x;
        As[(lq*4+1)*68 + lr] = a4.y;
        As[(lq*4+2)*68 + lr] = a4.z;
        As[(lq*4+3)*68 + lr] = a4.w;
        *(float4*)(Bs + br * 68 + bc * 4) = b4;
        __syncthreads();
#pragma unroll
        for (int kk = 0; kk < 16; ++kk) {
            float4 av = *(const float4*)(As + kk * 68 + ty * 4);
            float4 bv = *(const float4*)(Bs + kk * 68 + tx * 4);
            float aa[4] = {av.x, av.y, av.z, av.w};
            float bb[4] = {bv.x, bv.y, bv.z, bv.w};
#pragma unroll
            for (int i = 0; i < 4; ++i)
#pragma unroll
                for (int j = 0; j < 4; ++j) acc[i][j] += aa[i] * bb[j];
        }
        __syncthreads();
    }
    // ---- column-sum reduce: 16 partials per column -> Dlr in LDS ----
    part[tid] = cs;
    __syncthreads();
    if (tid < 64) {
        const int q = tid >> 2, e = tid & 3;
        float s = 0.f;
#pragma unroll
        for (int r = 0; r < 16; ++r) {
            const float* p4 = (const float*)&part[r * 16 + q];
            s += p4[e];
        }
        dlr[tid] = 1.f / (s + EPS_F);
    }
    __syncthreads();
    const float4 d4 = *(const float4*)(dlr + tx * 4);   // note: tx == bc
    // ---- An sweep: scale raw Am -> An in place (panel is L2-resident) ----
    for (int k0 = 0; k0 < 384; k0 += 16) {
        float* bp = Bp + (size_t)(k0 + br) * 384 + bc * 4;
        float4 v = *(const float4*)bp;
        v.x *= d4.x; v.y *= d4.y; v.z *= d4.z; v.w *= d4.w;
        *(float4*)bp = v;
    }
    // ---- out write, scaled by Dlr ----
    float* op = out + (size_t)batch * TV + w0 + tx * 4;
#pragma unroll
    for (int i = 0; i < 4; ++i) {
        float4 o4 = make_float4(acc[i][0] * d4.x, acc[i][1] * d4.y,
                                acc[i][2] * d4.z, acc[i][3] * d4.w);
        *(float4*)(op + (size_t)(ty * 4 + i) * 384) = o4;
    }
}

extern "C" void kernel_launch(void* const* d_in, const int* in_sizes, int n_in,
                              void* d_out, int out_size, void* d_ws, size_t ws_size,
                              hipStream_t stream) {
    const float* x  = (const float*)d_in[0];
    const float* A  = (const float*)d_in[1];
    const float* cw = (const float*)d_in[2];
    const float* cb = (const float*)d_in[3];
    const float* w1 = (const float*)d_in[4];
    const float* b1 = (const float*)d_in[5];
    const float* w2 = (const float*)d_in[6];
    const float* b2 = (const float*)d_in[7];
    const float* w3 = (const float*)d_in[8];
    const float* b3 = (const float*)d_in[9];

    float* out = (float*)d_out;
    float* An  = out + OUT0;                 // holds raw Am, scaled in place by k_gemm
    float* xc  = (float*)d_ws;               // 25165824 floats = 100.7 MB

    k_conv<<<768, 256, 0, stream>>>(x, cw, cb, xc);
    k_am  <<<6144, 384, 0, stream>>>(A, w1, b1, w2, b2, w3, b3, An);
    k_gemm<<<6144, 256, 0, stream>>>(xc, An, out);
}

// Round 4
// 1403.734 us; speedup vs baseline: 3.1873x; 1.0197x over previous
//
#include <hip/hip_runtime.h>

#define EPS_F 0.001f

constexpr int Nn = 16;
constexpr int Cc = 64;
constexpr int Tt = 64;
constexpr int Vv = 384;
constexpr size_t TV = (size_t)Tt * Vv;      // 24576
constexpr size_t VW = (size_t)Vv * Vv;      // 147456
constexpr size_t OUT0 = (size_t)Nn * Cc * TV;   // 25165824 floats (out)
// An: Nn*Cc*VW = 150994944 floats, appended after out in d_out

// ---------------- Kernel 1: xc[n,o,t,v] = sum_c x[n,c,t,v]*cw[o,c] + cb[o] ----
__global__ __launch_bounds__(256) void k_conv(const float* __restrict__ x,
        const float* __restrict__ cw, const float* __restrict__ cb,
        float* __restrict__ xc) {
    __shared__ float wt[64 * 64];   // transposed: wt[c*64+o]
    const int tid = threadIdx.x;
    for (int i = tid; i < 4096; i += 256) {
        int o = i & 63, c = i >> 6;
        wt[c * 64 + o] = cw[o * 64 + c];
    }
    __syncthreads();
    const int b = blockIdx.x;            // 768 blocks, 48 per n
    const int n = b / 48;
    const int pos = (b % 48) * 512 + tid;   // this thread handles pos and pos+256
    const float* xin = x + (size_t)n * Cc * TV + pos;
    float acc0[64], acc1[64];
#pragma unroll
    for (int o = 0; o < 64; ++o) { acc0[o] = 0.f; acc1[o] = 0.f; }
    for (int c = 0; c < 64; ++c) {
        float x0 = xin[(size_t)c * TV];
        float x1 = xin[(size_t)c * TV + 256];
        const float4* wr = (const float4*)(wt + c * 64);
#pragma unroll
        for (int oq = 0; oq < 16; ++oq) {
            float4 w4 = wr[oq];
            acc0[oq*4+0] += x0 * w4.x; acc0[oq*4+1] += x0 * w4.y;
            acc0[oq*4+2] += x0 * w4.z; acc0[oq*4+3] += x0 * w4.w;
            acc1[oq*4+0] += x1 * w4.x; acc1[oq*4+1] += x1 * w4.y;
            acc1[oq*4+2] += x1 * w4.z; acc1[oq*4+3] += x1 * w4.w;
        }
    }
    float* xo = xc + (size_t)n * Cc * TV + pos;
#pragma unroll
    for (int o = 0; o < 64; ++o) {
        float bo = cb[o];
        xo[(size_t)o * TV]       = acc0[o] + bo;
        xo[(size_t)o * TV + 256] = acc1[o] + bo;
    }
}

// ---------------- Kernel 2: Am[n,c,v,w] = relu(mlp(A))*mask  (UNscaled) ------
// All weights staged in LDS, read as broadcast float4 (conflict-free).
// Each thread computes TWO elements (v0,w) and (v0+1,w) so every weight read
// amortizes over 2x the FMAs -> VALU-dominant instead of load-dominant.
__global__ __launch_bounds__(384) void k_am(const float* __restrict__ A,
        const float* __restrict__ w1, const float* __restrict__ b1,
        const float* __restrict__ w2, const float* __restrict__ b2,
        const float* __restrict__ w3, const float* __restrict__ b3,
        float* __restrict__ Am) {
    __shared__ __align__(16) float sw1[16 * 8];   // rows padded 7 -> 8 (pad = 0)
    __shared__ __align__(16) float sw2[32 * 16];
    __shared__ __align__(16) float sw3[64 * 32];
    __shared__ float sb1[16], sb2[32], sb3[64];
    const int tid = threadIdx.x;
    if (tid < 128) {
        int o = tid >> 3, k = tid & 7;
        sw1[tid] = (k < 7) ? w1[o * 7 + k] : 0.f;
    }
    for (int i = tid; i < 512; i += 384)  sw2[i] = w2[i];
    for (int i = tid; i < 2048; i += 384) sw3[i] = w3[i];
    if (tid < 16) sb1[tid] = b1[tid];
    else if (tid < 48) sb2[tid - 16] = b2[tid - 16];
    else if (tid < 112) sb3[tid - 48] = b3[tid - 48];
    __syncthreads();

    const int b = blockIdx.x;           // n*192 + vpair
    const int n = b / 192;
    const int v0 = (b % 192) * 2;
    const float* Ab = A + (size_t)n * 8 * VW + (size_t)v0 * Vv + tid;
    float aA[8], aB[8];
#pragma unroll
    for (int k = 0; k < 8; ++k) {
        aA[k] = Ab[(size_t)k * VW];
        aB[k] = Ab[(size_t)k * VW + Vv];
    }
    // ---- layer 1: 8->16 (k=7 weight is 0, harmlessly multiplies the mask) ----
    float h1A[16], h1B[16];
#pragma unroll
    for (int o = 0; o < 16; ++o) {
        float4 wa = *(const float4*)(sw1 + o * 8);
        float4 wb = *(const float4*)(sw1 + o * 8 + 4);
        float tA = sb1[o], tB = sb1[o];
        tA += wa.x*aA[0] + wa.y*aA[1] + wa.z*aA[2] + wa.w*aA[3];
        tA += wb.x*aA[4] + wb.y*aA[5] + wb.z*aA[6] + wb.w*aA[7];
        tB += wa.x*aB[0] + wa.y*aB[1] + wa.z*aB[2] + wa.w*aB[3];
        tB += wb.x*aB[4] + wb.y*aB[5] + wb.z*aB[6] + wb.w*aB[7];
        h1A[o] = fmaxf(tA, 0.f);
        h1B[o] = fmaxf(tB, 0.f);
    }
    // ---- layer 2: 16->32 ----
    float h2A[32], h2B[32];
#pragma unroll
    for (int o = 0; o < 32; ++o) {
        const float4* wr = (const float4*)(sw2 + o * 16);
        float tA = sb2[o], tB = sb2[o];
#pragma unroll
        for (int q = 0; q < 4; ++q) {
            float4 w4 = wr[q];
            tA += w4.x*h1A[q*4+0] + w4.y*h1A[q*4+1] + w4.z*h1A[q*4+2] + w4.w*h1A[q*4+3];
            tB += w4.x*h1B[q*4+0] + w4.y*h1B[q*4+1] + w4.z*h1B[q*4+2] + w4.w*h1B[q*4+3];
        }
        h2A[o] = fmaxf(tA, 0.f);
        h2B[o] = fmaxf(tB, 0.f);
    }
    // ---- layer 3: 32->64, fused mask + store ----
    const float mA = aA[7], mB = aB[7];
    float* apA = Am + (size_t)n * 64 * VW + (size_t)v0 * Vv + tid;
#pragma unroll
    for (int o = 0; o < 64; ++o) {
        const float4* wr = (const float4*)(sw3 + o * 32);
        float tA = sb3[o], tB = sb3[o];
#pragma unroll
        for (int q = 0; q < 8; ++q) {
            float4 w4 = wr[q];
            tA += w4.x*h2A[q*4+0] + w4.y*h2A[q*4+1] + w4.z*h2A[q*4+2] + w4.w*h2A[q*4+3];
            tB += w4.x*h2B[q*4+0] + w4.y*h2B[q*4+1] + w4.z*h2B[q*4+2] + w4.w*h2B[q*4+3];
        }
        apA[(size_t)o * VW]      = fmaxf(tA, 0.f) * mA;
        apA[(size_t)o * VW + Vv] = fmaxf(tB, 0.f) * mB;
    }
}

// ---------------- Kernel 3: GEMM + fused column-sum + in-place An scaling ----
// out[b,t,w] = Dlr[b,w] * sum_v xc[b,t,v]*Am[b,v,w];  An = Am * Dlr.
// XCD-aware swizzle keeps the 6 w-tile blocks of one batch on one XCD so the
// shared xc panel is an L2 hit. Next k-tile is prefetched into registers
// before the compute phase to hide global-load latency.
__global__ __launch_bounds__(256) void k_gemm(const float* __restrict__ xc,
        float* __restrict__ An, float* __restrict__ out) {
    __shared__ float As[16 * 68];          // [k][t], padded
    __shared__ float Bs[16 * 68];          // [k][w], padded
    __shared__ float4 part[256];           // per-thread colsum partials
    __shared__ __align__(16) float dlr[64];
    const int tid = threadIdx.x;
    const int bid = blockIdx.x;            // 6144 = 8 * 768
    const int b = (bid & 7) * 768 + (bid >> 3);   // bijective XCD swizzle
    const int batch = b / 6;            // n*64+c
    const int w0 = (b % 6) * 64;
    const float* Ap = xc + (size_t)batch * TV;   // 64 x 384
    float* Bp = An + (size_t)batch * VW + w0;    // 384 x 384 (+col offset), raw Am
    const int ty = tid / 16, tx = tid % 16;
    const int lr = tid / 4,  lq = tid % 4;   // A-tile loader: row, k-quad
    const int br = tid / 16, bc = tid % 16;  // B-tile loader: k-row, w-quad
    float acc[4][4];
#pragma unroll
    for (int i = 0; i < 4; ++i)
#pragma unroll
        for (int j = 0; j < 4; ++j) acc[i][j] = 0.f;
    float4 cs = make_float4(0.f, 0.f, 0.f, 0.f);   // colsum partial (4 cols)
    float4 a4 = *(const float4*)(Ap + (size_t)lr * 384 + lq * 4);
    float4 b4 = *(const float4*)(Bp + (size_t)br * 384 + bc * 4);
    for (int k0 = 0; k0 < 384; k0 += 16) {
        cs.x += b4.x; cs.y += b4.y; cs.z += b4.z; cs.w += b4.w;
        As[(lq*4+0)*68 + lr] = a4.x;
        As[(lq*4+1)*68 + lr] = a4.y;
        As[(lq*4+2)*68 + lr] = a4.z;
        As[(lq*4+3)*68 + lr] = a4.w;
        *(float4*)(Bs + br * 68 + bc * 4) = b4;
        __syncthreads();
        if (k0 + 16 < 384) {   // prefetch next k-tile while LDS tile computes
            a4 = *(const float4*)(Ap + (size_t)lr * 384 + (k0 + 16) + lq * 4);
            b4 = *(const float4*)(Bp + (size_t)(k0 + 16 + br) * 384 + bc * 4);
        }
#pragma unroll
        for (int kk = 0; kk < 16; ++kk) {
            float4 av = *(const float4*)(As + kk * 68 + ty * 4);
            float4 bv = *(const float4*)(Bs + kk * 68 + tx * 4);
            float aa[4] = {av.x, av.y, av.z, av.w};
            float bb[4] = {bv.x, bv.y, bv.z, bv.w};
#pragma unroll
            for (int i = 0; i < 4; ++i)
#pragma unroll
                for (int j = 0; j < 4; ++j) acc[i][j] += aa[i] * bb[j];
        }
        __syncthreads();
    }
    // ---- column-sum reduce: 16 partials per column -> Dlr in LDS ----
    part[tid] = cs;
    __syncthreads();
    if (tid < 64) {
        const int q = tid >> 2, e = tid & 3;
        float s = 0.f;
#pragma unroll
        for (int r = 0; r < 16; ++r) {
            const float* p4 = (const float*)&part[r * 16 + q];
            s += p4[e];
        }
        dlr[tid] = 1.f / (s + EPS_F);
    }
    __syncthreads();
    const float4 d4 = *(const float4*)(dlr + tx * 4);   // note: tx == bc
    // ---- An sweep: scale raw Am -> An in place (panel is L2-resident) ----
    for (int k0 = 0; k0 < 384; k0 += 16) {
        float* bp = Bp + (size_t)(k0 + br) * 384 + bc * 4;
        float4 v = *(const float4*)bp;
        v.x *= d4.x; v.y *= d4.y; v.z *= d4.z; v.w *= d4.w;
        *(float4*)bp = v;
    }
    // ---- out write, scaled by Dlr ----
    float* op = out + (size_t)batch * TV + w0 + tx * 4;
#pragma unroll
    for (int i = 0; i < 4; ++i) {
        float4 o4 = make_float4(acc[i][0] * d4.x, acc[i][1] * d4.y,
                                acc[i][2] * d4.z, acc[i][3] * d4.w);
        *(float4*)(op + (size_t)(ty * 4 + i) * 384) = o4;
    }
}

extern "C" void kernel_launch(void* const* d_in, const int* in_sizes, int n_in,
                              void* d_out, int out_size, void* d_ws, size_t ws_size,
                              hipStream_t stream) {
    const float* x  = (const float*)d_in[0];
    const float* A  = (const float*)d_in[1];
    const float* cw = (const float*)d_in[2];
    const float* cb = (const float*)d_in[3];
    const float* w1 = (const float*)d_in[4];
    const float* b1 = (const float*)d_in[5];
    const float* w2 = (const float*)d_in[6];
    const float* b2 = (const float*)d_in[7];
    const float* w3 = (const float*)d_in[8];
    const float* b3 = (const float*)d_in[9];

    float* out = (float*)d_out;
    float* An  = out + OUT0;                 // holds raw Am, scaled in place by k_gemm
    float* xc  = (float*)d_ws;               // 25165824 floats = 100.7 MB

    k_conv<<<768, 256, 0, stream>>>(x, cw, cb, xc);
    k_am  <<<3072, 384, 0, stream>>>(A, w1, b1, w2, b2, w3, b3, An);
    k_gemm<<<6144, 256, 0, stream>>>(xc, An, out);
}

// Round 5
// 1353.829 us; speedup vs baseline: 3.3048x; 1.0369x over previous
//
#include <hip/hip_runtime.h>

#define EPS_F 0.001f

constexpr int Nn = 16;
constexpr int Cc = 64;
constexpr int Tt = 64;
constexpr int Vv = 384;
constexpr size_t TV = (size_t)Tt * Vv;      // 24576
constexpr size_t VW = (size_t)Vv * Vv;      // 147456
constexpr size_t OUT0 = (size_t)Nn * Cc * TV;   // 25165824 floats (out)
// An: Nn*Cc*VW = 150994944 floats, appended after out in d_out

// ---------------- Kernel 1: xc[n,o,t,v] = sum_c x[n,c,t,v]*cw[o,c] + cb[o] ----
__global__ __launch_bounds__(256) void k_conv(const float* __restrict__ x,
        const float* __restrict__ cw, const float* __restrict__ cb,
        float* __restrict__ xc) {
    __shared__ float wt[64 * 64];   // transposed: wt[c*64+o]
    const int tid = threadIdx.x;
    for (int i = tid; i < 4096; i += 256) {
        int o = i & 63, c = i >> 6;
        wt[c * 64 + o] = cw[o * 64 + c];
    }
    __syncthreads();
    const int b = blockIdx.x;            // 768 blocks, 48 per n
    const int n = b / 48;
    const int pos = (b % 48) * 512 + tid;   // this thread handles pos and pos+256
    const float* xin = x + (size_t)n * Cc * TV + pos;
    float acc0[64], acc1[64];
#pragma unroll
    for (int o = 0; o < 64; ++o) { acc0[o] = 0.f; acc1[o] = 0.f; }
    for (int c = 0; c < 64; ++c) {
        float x0 = xin[(size_t)c * TV];
        float x1 = xin[(size_t)c * TV + 256];
        const float4* wr = (const float4*)(wt + c * 64);
#pragma unroll
        for (int oq = 0; oq < 16; ++oq) {
            float4 w4 = wr[oq];
            acc0[oq*4+0] += x0 * w4.x; acc0[oq*4+1] += x0 * w4.y;
            acc0[oq*4+2] += x0 * w4.z; acc0[oq*4+3] += x0 * w4.w;
            acc1[oq*4+0] += x1 * w4.x; acc1[oq*4+1] += x1 * w4.y;
            acc1[oq*4+2] += x1 * w4.z; acc1[oq*4+3] += x1 * w4.w;
        }
    }
    float* xo = xc + (size_t)n * Cc * TV + pos;
#pragma unroll
    for (int o = 0; o < 64; ++o) {
        float bo = cb[o];
        xo[(size_t)o * TV]       = acc0[o] + bo;
        xo[(size_t)o * TV + 256] = acc1[o] + bo;
    }
}

// ---------------- Kernel 2: Am[n,c,v,w] = relu(mlp(A))*mask  (UNscaled) ------
__global__ __launch_bounds__(384) void k_am(const float* __restrict__ A,
        const float* __restrict__ w1, const float* __restrict__ b1,
        const float* __restrict__ w2, const float* __restrict__ b2,
        const float* __restrict__ w3, const float* __restrict__ b3,
        float* __restrict__ Am) {
    __shared__ __align__(16) float sw1[16 * 8];   // rows padded 7 -> 8 (pad = 0)
    __shared__ __align__(16) float sw2[32 * 16];
    __shared__ __align__(16) float sw3[64 * 32];
    __shared__ float sb1[16], sb2[32], sb3[64];
    const int tid = threadIdx.x;
    if (tid < 128) {
        int o = tid >> 3, k = tid & 7;
        sw1[tid] = (k < 7) ? w1[o * 7 + k] : 0.f;
    }
    for (int i = tid; i < 512; i += 384)  sw2[i] = w2[i];
    for (int i = tid; i < 2048; i += 384) sw3[i] = w3[i];
    if (tid < 16) sb1[tid] = b1[tid];
    else if (tid < 48) sb2[tid - 16] = b2[tid - 16];
    else if (tid < 112) sb3[tid - 48] = b3[tid - 48];
    __syncthreads();

    const int b = blockIdx.x;           // n*192 + vpair
    const int n = b / 192;
    const int v0 = (b % 192) * 2;
    const float* Ab = A + (size_t)n * 8 * VW + (size_t)v0 * Vv + tid;
    float aA[8], aB[8];
#pragma unroll
    for (int k = 0; k < 8; ++k) {
        aA[k] = Ab[(size_t)k * VW];
        aB[k] = Ab[(size_t)k * VW + Vv];
    }
    float h1A[16], h1B[16];
#pragma unroll
    for (int o = 0; o < 16; ++o) {
        float4 wa = *(const float4*)(sw1 + o * 8);
        float4 wb = *(const float4*)(sw1 + o * 8 + 4);
        float tA = sb1[o], tB = sb1[o];
        tA += wa.x*aA[0] + wa.y*aA[1] + wa.z*aA[2] + wa.w*aA[3];
        tA += wb.x*aA[4] + wb.y*aA[5] + wb.z*aA[6] + wb.w*aA[7];
        tB += wa.x*aB[0] + wa.y*aB[1] + wa.z*aB[2] + wa.w*aB[3];
        tB += wb.x*aB[4] + wb.y*aB[5] + wb.z*aB[6] + wb.w*aB[7];
        h1A[o] = fmaxf(tA, 0.f);
        h1B[o] = fmaxf(tB, 0.f);
    }
    float h2A[32], h2B[32];
#pragma unroll
    for (int o = 0; o < 32; ++o) {
        const float4* wr = (const float4*)(sw2 + o * 16);
        float tA = sb2[o], tB = sb2[o];
#pragma unroll
        for (int q = 0; q < 4; ++q) {
            float4 w4 = wr[q];
            tA += w4.x*h1A[q*4+0] + w4.y*h1A[q*4+1] + w4.z*h1A[q*4+2] + w4.w*h1A[q*4+3];
            tB += w4.x*h1B[q*4+0] + w4.y*h1B[q*4+1] + w4.z*h1B[q*4+2] + w4.w*h1B[q*4+3];
        }
        h2A[o] = fmaxf(tA, 0.f);
        h2B[o] = fmaxf(tB, 0.f);
    }
    const float mA = aA[7], mB = aB[7];
    float* apA = Am + (size_t)n * 64 * VW + (size_t)v0 * Vv + tid;
#pragma unroll
    for (int o = 0; o < 64; ++o) {
        const float4* wr = (const float4*)(sw3 + o * 32);
        float tA = sb3[o], tB = sb3[o];
#pragma unroll
        for (int q = 0; q < 8; ++q) {
            float4 w4 = wr[q];
            tA += w4.x*h2A[q*4+0] + w4.y*h2A[q*4+1] + w4.z*h2A[q*4+2] + w4.w*h2A[q*4+3];
            tB += w4.x*h2B[q*4+0] + w4.y*h2B[q*4+1] + w4.z*h2B[q*4+2] + w4.w*h2B[q*4+3];
        }
        apA[(size_t)o * VW]      = fmaxf(tA, 0.f) * mA;
        apA[(size_t)o * VW + Vv] = fmaxf(tB, 0.f) * mB;
    }
}

// ---------------- Kernel 3: single-wave GEMM + colsum + in-place An scale ----
// One 64-lane wave per block -> no __syncthreads at all (LDS ops are in-order
// within a wave; explicit lgkmcnt(0) after staging). 8x8 register tile per
// lane -> 4 broadcast ds_read_b128 per 64 FMA (LDS pipe no longer the limit).
// Register prefetch of the next k-tile stays in flight across staging (no
// vmcnt(0) drain since there is no barrier).
__global__ __launch_bounds__(64) void k_gemm(const float* __restrict__ xc,
        float* __restrict__ An, float* __restrict__ out) {
    __shared__ float As[16][68];           // [k][t], padded
    __shared__ float Bs[16][68];           // [k][w], padded
    __shared__ __align__(16) float dlr[64];
    const int tid = threadIdx.x;
    const int bid = blockIdx.x;            // 6144 = 8 * 768
    const int b = (bid & 7) * 768 + (bid >> 3);   // bijective XCD swizzle
    const int batch = b / 6;               // n*64+c
    const int w0 = (b % 6) * 64;
    const float* Ap = xc + (size_t)batch * TV;    // 64 x 384
    float* Bp = An + (size_t)batch * VW + w0;     // 384 x 384 (+col offset), raw Am

    const int lq = tid & 3,  lr4 = tid >> 2;   // A loader: k-quad, row-group
    const int c4 = tid & 15, rg  = tid >> 4;   // B loader: col-quad, row-group
    const int tx = tid & 7,  ty  = tid >> 3;   // compute: col-oct, row-oct

    float4 ap[4], bp[4];
#pragma unroll
    for (int i = 0; i < 4; ++i) {
        ap[i] = *(const float4*)(Ap + (size_t)(lr4 * 4 + i) * 384 + lq * 4);
        bp[i] = *(const float4*)(Bp + (size_t)(rg * 4 + i) * 384 + c4 * 4);
    }
    float4 cs = make_float4(0.f, 0.f, 0.f, 0.f);
    float acc[8][8];
#pragma unroll
    for (int i = 0; i < 8; ++i)
#pragma unroll
        for (int j = 0; j < 8; ++j) acc[i][j] = 0.f;

    for (int k0 = 0; k0 < 384; k0 += 16) {
        // ---- stage regs -> LDS, accumulate colsum ----
#pragma unroll
        for (int i = 0; i < 4; ++i) {
            As[lq*4+0][lr4*4+i] = ap[i].x;
            As[lq*4+1][lr4*4+i] = ap[i].y;
            As[lq*4+2][lr4*4+i] = ap[i].z;
            As[lq*4+3][lr4*4+i] = ap[i].w;
            *(float4*)&Bs[rg*4+i][c4*4] = bp[i];
            cs.x += bp[i].x; cs.y += bp[i].y; cs.z += bp[i].z; cs.w += bp[i].w;
        }
        asm volatile("s_waitcnt lgkmcnt(0)" ::: "memory");
        __builtin_amdgcn_sched_barrier(0);
        // ---- issue prefetch of next k-tile (stays in flight over compute) ----
        if (k0 + 16 < 384) {
#pragma unroll
            for (int i = 0; i < 4; ++i) {
                ap[i] = *(const float4*)(Ap + (size_t)(lr4*4+i) * 384 + (k0+16) + lq*4);
                bp[i] = *(const float4*)(Bp + (size_t)(k0+16 + rg*4+i) * 384 + c4*4);
            }
        }
        // ---- compute 16 k-slices from LDS (broadcast reads) ----
#pragma unroll
        for (int kk = 0; kk < 16; ++kk) {
            float4 a0 = *(const float4*)&As[kk][ty*8];
            float4 a1 = *(const float4*)&As[kk][ty*8+4];
            float4 b0 = *(const float4*)&Bs[kk][tx*4];
            float4 b1 = *(const float4*)&Bs[kk][tx*4+32];
            float av[8] = {a0.x,a0.y,a0.z,a0.w,a1.x,a1.y,a1.z,a1.w};
            float bv[8] = {b0.x,b0.y,b0.z,b0.w,b1.x,b1.y,b1.z,b1.w};
#pragma unroll
            for (int i = 0; i < 8; ++i)
#pragma unroll
                for (int j = 0; j < 8; ++j) acc[i][j] += av[i] * bv[j];
        }
    }
    // ---- colsum reduce across the 4 row-groups (lanes c4, c4+16, +32, +48) --
    cs.x += __shfl_xor(cs.x, 16); cs.y += __shfl_xor(cs.y, 16);
    cs.z += __shfl_xor(cs.z, 16); cs.w += __shfl_xor(cs.w, 16);
    cs.x += __shfl_xor(cs.x, 32); cs.y += __shfl_xor(cs.y, 32);
    cs.z += __shfl_xor(cs.z, 32); cs.w += __shfl_xor(cs.w, 32);
    if (tid < 16) {
        float4 r;
        r.x = 1.f / (cs.x + EPS_F); r.y = 1.f / (cs.y + EPS_F);
        r.z = 1.f / (cs.z + EPS_F); r.w = 1.f / (cs.w + EPS_F);
        *(float4*)&dlr[tid * 4] = r;
    }
    asm volatile("s_waitcnt lgkmcnt(0)" ::: "memory");
    // ---- An sweep: scale raw Am -> An in place (panel is L2-resident) ----
    {
        const float4 dc = *(const float4*)&dlr[c4 * 4];
        float* sp = Bp + (size_t)rg * 384 + c4 * 4;
#pragma unroll 4
        for (int it = 0; it < 96; ++it) {
            float4 v = *(const float4*)sp;
            v.x *= dc.x; v.y *= dc.y; v.z *= dc.z; v.w *= dc.w;
            *(float4*)sp = v;
            sp += 4 * 384;
        }
    }
    // ---- out write, scaled by Dlr ----
    const float4 da = *(const float4*)&dlr[tx * 4];
    const float4 db = *(const float4*)&dlr[tx * 4 + 32];
    float* op = out + (size_t)batch * TV + w0;
#pragma unroll
    for (int i = 0; i < 8; ++i) {
        float4 o0 = make_float4(acc[i][0]*da.x, acc[i][1]*da.y,
                                acc[i][2]*da.z, acc[i][3]*da.w);
        float4 o1 = make_float4(acc[i][4]*db.x, acc[i][5]*db.y,
                                acc[i][6]*db.z, acc[i][7]*db.w);
        *(float4*)(op + (size_t)(ty*8+i) * 384 + tx*4)      = o0;
        *(float4*)(op + (size_t)(ty*8+i) * 384 + tx*4 + 32) = o1;
    }
}

extern "C" void kernel_launch(void* const* d_in, const int* in_sizes, int n_in,
                              void* d_out, int out_size, void* d_ws, size_t ws_size,
                              hipStream_t stream) {
    const float* x  = (const float*)d_in[0];
    const float* A  = (const float*)d_in[1];
    const float* cw = (const float*)d_in[2];
    const float* cb = (const float*)d_in[3];
    const float* w1 = (const float*)d_in[4];
    const float* b1 = (const float*)d_in[5];
    const float* w2 = (const float*)d_in[6];
    const float* b2 = (const float*)d_in[7];
    const float* w3 = (const float*)d_in[8];
    const float* b3 = (const float*)d_in[9];

    float* out = (float*)d_out;
    float* An  = out + OUT0;                 // holds raw Am, scaled in place by k_gemm
    float* xc  = (float*)d_ws;               // 25165824 floats = 100.7 MB

    k_conv<<<768, 256, 0, stream>>>(x, cw, cb, xc);
    k_am  <<<3072, 384, 0, stream>>>(A, w1, b1, w2, b2, w3, b3, An);
    k_gemm<<<6144, 64, 0, stream>>>(xc, An, out);
}

// Round 6
// 1288.257 us; speedup vs baseline: 3.4730x; 1.0509x over previous
//
#include <hip/hip_runtime.h>

#define EPS_F 0.001f

constexpr int Nn = 16;
constexpr int Cc = 64;
constexpr int Tt = 64;
constexpr int Vv = 384;
constexpr size_t TV = (size_t)Tt * Vv;      // 24576
constexpr size_t VW = (size_t)Vv * Vv;      // 147456
constexpr size_t OUT0 = (size_t)Nn * Cc * TV;   // 25165824 floats (out)
// An: Nn*Cc*VW = 150994944 floats, appended after out in d_out

// ---------------- Kernel 1: xc[n,o,t,v] = sum_c x[n,c,t,v]*cw[o,c] + cb[o] ----
__global__ __launch_bounds__(256) void k_conv(const float* __restrict__ x,
        const float* __restrict__ cw, const float* __restrict__ cb,
        float* __restrict__ xc) {
    __shared__ float wt[64 * 64];   // transposed: wt[c*64+o]
    const int tid = threadIdx.x;
    for (int i = tid; i < 4096; i += 256) {
        int o = i & 63, c = i >> 6;
        wt[c * 64 + o] = cw[o * 64 + c];
    }
    __syncthreads();
    const int b = blockIdx.x;            // 768 blocks, 48 per n
    const int n = b / 48;
    const int pos = (b % 48) * 512 + tid;   // this thread handles pos and pos+256
    const float* xin = x + (size_t)n * Cc * TV + pos;
    float acc0[64], acc1[64];
#pragma unroll
    for (int o = 0; o < 64; ++o) { acc0[o] = 0.f; acc1[o] = 0.f; }
    for (int c = 0; c < 64; ++c) {
        float x0 = xin[(size_t)c * TV];
        float x1 = xin[(size_t)c * TV + 256];
        const float4* wr = (const float4*)(wt + c * 64);
#pragma unroll
        for (int oq = 0; oq < 16; ++oq) {
            float4 w4 = wr[oq];
            acc0[oq*4+0] += x0 * w4.x; acc0[oq*4+1] += x0 * w4.y;
            acc0[oq*4+2] += x0 * w4.z; acc0[oq*4+3] += x0 * w4.w;
            acc1[oq*4+0] += x1 * w4.x; acc1[oq*4+1] += x1 * w4.y;
            acc1[oq*4+2] += x1 * w4.z; acc1[oq*4+3] += x1 * w4.w;
        }
    }
    float* xo = xc + (size_t)n * Cc * TV + pos;
#pragma unroll
    for (int o = 0; o < 64; ++o) {
        float bo = cb[o];
        xo[(size_t)o * TV]       = acc0[o] + bo;
        xo[(size_t)o * TV + 256] = acc1[o] + bo;
    }
}

// ---------------- Kernel 2: Am[n,c,v,w] = relu(mlp(A))*mask  (UNscaled) ------
__global__ __launch_bounds__(384) void k_am(const float* __restrict__ A,
        const float* __restrict__ w1, const float* __restrict__ b1,
        const float* __restrict__ w2, const float* __restrict__ b2,
        const float* __restrict__ w3, const float* __restrict__ b3,
        float* __restrict__ Am) {
    __shared__ __align__(16) float sw1[16 * 8];   // rows padded 7 -> 8 (pad = 0)
    __shared__ __align__(16) float sw2[32 * 16];
    __shared__ __align__(16) float sw3[64 * 32];
    __shared__ float sb1[16], sb2[32], sb3[64];
    const int tid = threadIdx.x;
    if (tid < 128) {
        int o = tid >> 3, k = tid & 7;
        sw1[tid] = (k < 7) ? w1[o * 7 + k] : 0.f;
    }
    for (int i = tid; i < 512; i += 384)  sw2[i] = w2[i];
    for (int i = tid; i < 2048; i += 384) sw3[i] = w3[i];
    if (tid < 16) sb1[tid] = b1[tid];
    else if (tid < 48) sb2[tid - 16] = b2[tid - 16];
    else if (tid < 112) sb3[tid - 48] = b3[tid - 48];
    __syncthreads();

    const int b = blockIdx.x;           // n*192 + vpair
    const int n = b / 192;
    const int v0 = (b % 192) * 2;
    const float* Ab = A + (size_t)n * 8 * VW + (size_t)v0 * Vv + tid;
    float aA[8], aB[8];
#pragma unroll
    for (int k = 0; k < 8; ++k) {
        aA[k] = Ab[(size_t)k * VW];
        aB[k] = Ab[(size_t)k * VW + Vv];
    }
    float h1A[16], h1B[16];
#pragma unroll
    for (int o = 0; o < 16; ++o) {
        float4 wa = *(const float4*)(sw1 + o * 8);
        float4 wb = *(const float4*)(sw1 + o * 8 + 4);
        float tA = sb1[o], tB = sb1[o];
        tA += wa.x*aA[0] + wa.y*aA[1] + wa.z*aA[2] + wa.w*aA[3];
        tA += wb.x*aA[4] + wb.y*aA[5] + wb.z*aA[6] + wb.w*aA[7];
        tB += wa.x*aB[0] + wa.y*aB[1] + wa.z*aB[2] + wa.w*aB[3];
        tB += wb.x*aB[4] + wb.y*aB[5] + wb.z*aB[6] + wb.w*aB[7];
        h1A[o] = fmaxf(tA, 0.f);
        h1B[o] = fmaxf(tB, 0.f);
    }
    float h2A[32], h2B[32];
#pragma unroll
    for (int o = 0; o < 32; ++o) {
        const float4* wr = (const float4*)(sw2 + o * 16);
        float tA = sb2[o], tB = sb2[o];
#pragma unroll
        for (int q = 0; q < 4; ++q) {
            float4 w4 = wr[q];
            tA += w4.x*h1A[q*4+0] + w4.y*h1A[q*4+1] + w4.z*h1A[q*4+2] + w4.w*h1A[q*4+3];
            tB += w4.x*h1B[q*4+0] + w4.y*h1B[q*4+1] + w4.z*h1B[q*4+2] + w4.w*h1B[q*4+3];
        }
        h2A[o] = fmaxf(tA, 0.f);
        h2B[o] = fmaxf(tB, 0.f);
    }
    const float mA = aA[7], mB = aB[7];
    float* apA = Am + (size_t)n * 64 * VW + (size_t)v0 * Vv + tid;
#pragma unroll
    for (int o = 0; o < 64; ++o) {
        const float4* wr = (const float4*)(sw3 + o * 32);
        float tA = sb3[o], tB = sb3[o];
#pragma unroll
        for (int q = 0; q < 8; ++q) {
            float4 w4 = wr[q];
            tA += w4.x*h2A[q*4+0] + w4.y*h2A[q*4+1] + w4.z*h2A[q*4+2] + w4.w*h2A[q*4+3];
            tB += w4.x*h2B[q*4+0] + w4.y*h2B[q*4+1] + w4.z*h2B[q*4+2] + w4.w*h2B[q*4+3];
        }
        apA[(size_t)o * VW]      = fmaxf(tA, 0.f) * mA;
        apA[(size_t)o * VW + Vv] = fmaxf(tB, 0.f) * mB;
    }
}

// ---------------- Kernel 3: 4 independent single-wave GEMMs per workgroup ----
// Per-wave structure identical to round 5 (8x8 tile, no barriers, register
// prefetch, fused colsum + in-place An scale). Packing 4 waves per 256-thread
// workgroup fixes the workgroup-residency cap that throttled HBM demand
// (occupancy 11% -> each resident workgroup now carries 4 waves).
__global__ __launch_bounds__(256) void k_gemm(const float* __restrict__ xc,
        float* __restrict__ An, float* __restrict__ out) {
    __shared__ float As[4][16][68];        // per-wave [k][t], padded
    __shared__ float Bs[4][16][68];        // per-wave [k][w], padded
    __shared__ __align__(16) float dlr[4][64];
    const int tid = threadIdx.x;
    const int wv = tid >> 6;               // wave id 0..3
    const int lane = tid & 63;
    const int W = blockIdx.x;              // 1536 = 8 XCD * 192
    // XCD-contiguous bijective map: XCD x owns b in [x*768, (x+1)*768)
    const int b = (W & 7) * 768 + (W >> 3) * 4 + wv;
    const int batch = b / 6;               // n*64+c
    const int w0 = (b % 6) * 64;
    const float* Ap = xc + (size_t)batch * TV;    // 64 x 384
    float* Bp = An + (size_t)batch * VW + w0;     // 384 x 384 (+col offset), raw Am

    const int lq = lane & 3,  lr4 = lane >> 2;   // A loader: k-quad, row-group
    const int c4 = lane & 15, rg  = lane >> 4;   // B loader: col-quad, row-group
    const int tx = lane & 7,  ty  = lane >> 3;   // compute: col-oct, row-oct

    float4 ap[4], bp[4];
#pragma unroll
    for (int i = 0; i < 4; ++i) {
        ap[i] = *(const float4*)(Ap + (size_t)(lr4 * 4 + i) * 384 + lq * 4);
        bp[i] = *(const float4*)(Bp + (size_t)(rg * 4 + i) * 384 + c4 * 4);
    }
    float4 cs = make_float4(0.f, 0.f, 0.f, 0.f);
    float acc[8][8];
#pragma unroll
    for (int i = 0; i < 8; ++i)
#pragma unroll
        for (int j = 0; j < 8; ++j) acc[i][j] = 0.f;

    for (int k0 = 0; k0 < 384; k0 += 16) {
        // ---- stage regs -> LDS, accumulate colsum ----
#pragma unroll
        for (int i = 0; i < 4; ++i) {
            As[wv][lq*4+0][lr4*4+i] = ap[i].x;
            As[wv][lq*4+1][lr4*4+i] = ap[i].y;
            As[wv][lq*4+2][lr4*4+i] = ap[i].z;
            As[wv][lq*4+3][lr4*4+i] = ap[i].w;
            *(float4*)&Bs[wv][rg*4+i][c4*4] = bp[i];
            cs.x += bp[i].x; cs.y += bp[i].y; cs.z += bp[i].z; cs.w += bp[i].w;
        }
        asm volatile("s_waitcnt lgkmcnt(0)" ::: "memory");
        __builtin_amdgcn_sched_barrier(0);
        // ---- issue prefetch of next k-tile (stays in flight over compute) ----
        if (k0 + 16 < 384) {
#pragma unroll
            for (int i = 0; i < 4; ++i) {
                ap[i] = *(const float4*)(Ap + (size_t)(lr4*4+i) * 384 + (k0+16) + lq*4);
                bp[i] = *(const float4*)(Bp + (size_t)(k0+16 + rg*4+i) * 384 + c4*4);
            }
        }
        // ---- compute 16 k-slices from LDS (broadcast reads) ----
#pragma unroll
        for (int kk = 0; kk < 16; ++kk) {
            float4 a0 = *(const float4*)&As[wv][kk][ty*8];
            float4 a1 = *(const float4*)&As[wv][kk][ty*8+4];
            float4 b0 = *(const float4*)&Bs[wv][kk][tx*4];
            float4 b1 = *(const float4*)&Bs[wv][kk][tx*4+32];
            float av[8] = {a0.x,a0.y,a0.z,a0.w,a1.x,a1.y,a1.z,a1.w};
            float bv[8] = {b0.x,b0.y,b0.z,b0.w,b1.x,b1.y,b1.z,b1.w};
#pragma unroll
            for (int i = 0; i < 8; ++i)
#pragma unroll
                for (int j = 0; j < 8; ++j) acc[i][j] += av[i] * bv[j];
        }
    }
    // ---- colsum reduce across the 4 row-groups (lanes c4, c4+16, +32, +48) --
    cs.x += __shfl_xor(cs.x, 16); cs.y += __shfl_xor(cs.y, 16);
    cs.z += __shfl_xor(cs.z, 16); cs.w += __shfl_xor(cs.w, 16);
    cs.x += __shfl_xor(cs.x, 32); cs.y += __shfl_xor(cs.y, 32);
    cs.z += __shfl_xor(cs.z, 32); cs.w += __shfl_xor(cs.w, 32);
    if (lane < 16) {
        float4 r;
        r.x = 1.f / (cs.x + EPS_F); r.y = 1.f / (cs.y + EPS_F);
        r.z = 1.f / (cs.z + EPS_F); r.w = 1.f / (cs.w + EPS_F);
        *(float4*)&dlr[wv][lane * 4] = r;
    }
    asm volatile("s_waitcnt lgkmcnt(0)" ::: "memory");
    // ---- An sweep: scale raw Am -> An in place (panel is L2-resident) ----
    {
        const float4 dc = *(const float4*)&dlr[wv][c4 * 4];
        float* sp = Bp + (size_t)rg * 384 + c4 * 4;
#pragma unroll 4
        for (int it = 0; it < 96; ++it) {
            float4 v = *(const float4*)sp;
            v.x *= dc.x; v.y *= dc.y; v.z *= dc.z; v.w *= dc.w;
            *(float4*)sp = v;
            sp += 4 * 384;
        }
    }
    // ---- out write, scaled by Dlr ----
    const float4 da = *(const float4*)&dlr[wv][tx * 4];
    const float4 db = *(const float4*)&dlr[wv][tx * 4 + 32];
    float* op = out + (size_t)batch * TV + w0;
#pragma unroll
    for (int i = 0; i < 8; ++i) {
        float4 o0 = make_float4(acc[i][0]*da.x, acc[i][1]*da.y,
                                acc[i][2]*da.z, acc[i][3]*da.w);
        float4 o1 = make_float4(acc[i][4]*db.x, acc[i][5]*db.y,
                                acc[i][6]*db.z, acc[i][7]*db.w);
        *(float4*)(op + (size_t)(ty*8+i) * 384 + tx*4)      = o0;
        *(float4*)(op + (size_t)(ty*8+i) * 384 + tx*4 + 32) = o1;
    }
}

extern "C" void kernel_launch(void* const* d_in, const int* in_sizes, int n_in,
                              void* d_out, int out_size, void* d_ws, size_t ws_size,
                              hipStream_t stream) {
    const float* x  = (const float*)d_in[0];
    const float* A  = (const float*)d_in[1];
    const float* cw = (const float*)d_in[2];
    const float* cb = (const float*)d_in[3];
    const float* w1 = (const float*)d_in[4];
    const float* b1 = (const float*)d_in[5];
    const float* w2 = (const float*)d_in[6];
    const float* b2 = (const float*)d_in[7];
    const float* w3 = (const float*)d_in[8];
    const float* b3 = (const float*)d_in[9];

    float* out = (float*)d_out;
    float* An  = out + OUT0;                 // holds raw Am, scaled in place by k_gemm
    float* xc  = (float*)d_ws;               // 25165824 floats = 100.7 MB

    k_conv<<<768, 256, 0, stream>>>(x, cw, cb, xc);
    k_am  <<<3072, 384, 0, stream>>>(A, w1, b1, w2, b2, w3, b3, An);
    k_gemm<<<1536, 256, 0, stream>>>(xc, An, out);
}